// Round 3
// baseline (326.332 us; speedup 1.0000x reference)
//
#include <hip/hip_runtime.h>

// B=8, N=32, T=64, D=128, E=4, H=32, BT=512
// R12: decisive test between (H1) residual scratch/demotion traffic and
// (H2) counter-inflation + latency convoys. Changes:
//  - k2 peak live VGPRs < ~100 everywhere (thf no longer held across P6;
//    loaded inside P7 from L2-hot Wfrag). launch_bounds(256,3).
//  - wave-parallel softmax (8 lanes/row, shfl_xor) replaces 32-thread serial.
//  - LDS 52->43.5KB (V reg-staged in P0, written to dead Ks region post-P3;
//    Sfrag packed in same region) -> 3 blocks/CU.
//  - edge/prior loads hoisted to kernel top; prior->log folded at arrival.
//  - k1 streams B-frags in-loop (no 112-reg prefetch array).
// Numerics identical to R11 except softmax denominator tree-sum (~1ulp).

typedef __bf16 bf16x8 __attribute__((ext_vector_type(8)));
typedef float  f32x4  __attribute__((ext_vector_type(4)));

static __device__ __forceinline__ unsigned short f2bf(float f) {
    unsigned u = __float_as_uint(f);
    u += 0x7fffu + ((u >> 16) & 1u);        // RNE
    return (unsigned short)(u >> 16);
}
static __device__ __forceinline__ float bf2f(unsigned short u) {
    return __uint_as_float(((unsigned)u) << 16);
}
static __device__ __forceinline__ unsigned pack2(float a, float b) {
    return (unsigned)f2bf(a) | ((unsigned)f2bf(b) << 16);
}

// ---------------------------------------------------------------------------
// Wfrag (16B chunks): [0,2048) Wq | [2048,4096) Wk | [4096,6144) Wv |
// [6144,8192) Theta | chunk 8192+: Cq=W1q@Wq (512), chunk 8704+: Ck=W1k@Wk (512).
// B-frag chunk (nt*4+ks)*64+lane holds B[k=j][n]: n = nt*16+(lane&15),
// j = ks*32+(lane>>4)*8 + (0..7).
// ---------------------------------------------------------------------------

__global__ __launch_bounds__(256) void k0_prep(
    const float* __restrict__ Wq, const float* __restrict__ Wk,
    const float* __restrict__ Wv, const float* __restrict__ Theta,
    const float* __restrict__ W1, unsigned short* __restrict__ Wfrag)
{
    const int tid = threadIdx.x;
    if (blockIdx.x < 32) {
        int gid = blockIdx.x * 256 + tid;      // 0..8191
        int g = gid >> 11, c = gid & 2047;
        int ntk = c >> 6, lane = c & 63;
        int i = (ntk >> 2) * 16 + (lane & 15);
        int j = (ntk & 3) * 32 + (lane >> 4) * 8;
        const float* src = (g == 0 ? Wq : g == 1 ? Wk : g == 2 ? Wv : Theta) + (size_t)i * 128 + j;
        float4 a = *(const float4*)(src);
        float4 b = *(const float4*)(src + 4);
        uint4 pk;
        pk.x = pack2(a.x, a.y); pk.y = pack2(a.z, a.w);
        pk.z = pack2(b.x, b.y); pk.w = pack2(b.z, b.w);
        *(uint4*)(Wfrag + (size_t)gid * 8) = pk;
    } else {
        // compose Cq = W1q@Wq, Ck = W1k@Wk
        int b2 = blockIdx.x - 32;              // 0..31
        int mat = b2 & 1;
        int hbase = (b2 >> 1) * 2;
        int hl = tid >> 7, col = tid & 127;
        int h = hbase + hl;
        const float* Wsel = mat ? Wk : Wq;
        const float* w1r = W1 + (size_t)h * 260 + mat * 128;
        float acc = 0.f;
        for (int i = 0; i < 128; ++i)
            acc = fmaf(w1r[i], Wsel[(size_t)i * 128 + col], acc);
        int nt = h >> 4;
        unsigned base = 65536u + (unsigned)mat * 4096u;   // shorts
        int lane = (h & 15) | (((col >> 3) & 3) << 4);
        int ks = col >> 5, vj = col & 7;
        Wfrag[base + (unsigned)((nt * 4 + ks) * 64 + lane) * 8 + vj] = f2bf(acc);
    }
}

// ===== projection GEMM: M=16384 tokens, N=448 (Q|K|V|hq|hk), K=128 ==========
// grid 512 x 256 (32 tokens/block). B-frags streamed in-loop from L2-resident
// Wfrag (no big register prefetch -> ~70 VGPR, no demotion possible).
__global__ __launch_bounds__(256, 2)
void k1_proj(const float* __restrict__ x,
             const unsigned short* __restrict__ Wfrag,
             const float* __restrict__ b1,
             float* __restrict__ Qws, float* __restrict__ Kws,
             unsigned short* __restrict__ Vws,
             unsigned short* __restrict__ hqws, unsigned short* __restrict__ hkws)
{
    __shared__ __align__(16) unsigned short Zf[512 * 8];     // 8 KB
    const int tid = threadIdx.x;
    const int Mbase = blockIdx.x * 32;

#pragma unroll
    for (int it = 0; it < 2; ++it) {
        int f = tid + 256 * it;                 // chunk 0..511
        int lane9 = f & 63, tk = f >> 6;        // tk 0..7
        int nl = (tk >> 2) * 16 + (lane9 & 15); // token-local 0..31
        int d  = (tk & 3) * 32 + (lane9 >> 4) * 8;
        int tok = Mbase + nl;
        int n = tok & 31, bt = tok >> 5;
        int b_ = bt >> 6, t_ = bt & 63;
        const float* xr = x + ((size_t)((b_ * 32 + n) * 64 + t_)) * 128 + d;
        float4 a = *(const float4*)(xr);
        float4 b = *(const float4*)(xr + 4);
        uint4 pk;
        pk.x = pack2(a.x, a.y); pk.y = pack2(a.z, a.w);
        pk.z = pack2(b.x, b.y); pk.w = pack2(b.z, b.w);
        *(uint4*)(Zf + f * 8) = pk;
    }
    __syncthreads();

    const int wv = tid >> 6, lane = tid & 63;
    const int quad = lane >> 4, col0 = lane & 15;
    const float b1lo = b1[col0], b1hi = b1[16 + col0];
    const bf16x8* Wf = (const bf16x8*)Wfrag;

    bf16x8 avZ[2][4];   // [token-group][ks] -- static indexing only
#pragma unroll
    for (int tg = 0; tg < 2; ++tg)
#pragma unroll
        for (int ks = 0; ks < 4; ++ks)
            avZ[tg][ks] = *(const bf16x8*)(Zf + ((tg * 4 + ks) * 64 + lane) * 8);

    const f32x4 zero = {0.f, 0.f, 0.f, 0.f};
#pragma unroll
    for (int k7 = 0; k7 < 7; ++k7) {
        const int nt = wv + k7 * 4;             // wave-uniform
        const int cbase = (nt < 24) ? nt * 256 : 8192 + (nt - 24) * 256;
        bf16x8 bw0 = Wf[cbase + 0 * 64 + lane];
        bf16x8 bw1 = Wf[cbase + 1 * 64 + lane];
        bf16x8 bw2 = Wf[cbase + 2 * 64 + lane];
        bf16x8 bw3 = Wf[cbase + 3 * 64 + lane];
        f32x4 acc0 = zero, acc1 = zero;
        acc0 = __builtin_amdgcn_mfma_f32_16x16x32_bf16(avZ[0][0], bw0, acc0, 0, 0, 0);
        acc1 = __builtin_amdgcn_mfma_f32_16x16x32_bf16(avZ[1][0], bw0, acc1, 0, 0, 0);
        acc0 = __builtin_amdgcn_mfma_f32_16x16x32_bf16(avZ[0][1], bw1, acc0, 0, 0, 0);
        acc1 = __builtin_amdgcn_mfma_f32_16x16x32_bf16(avZ[1][1], bw1, acc1, 0, 0, 0);
        acc0 = __builtin_amdgcn_mfma_f32_16x16x32_bf16(avZ[0][2], bw2, acc0, 0, 0, 0);
        acc1 = __builtin_amdgcn_mfma_f32_16x16x32_bf16(avZ[1][2], bw2, acc1, 0, 0, 0);
        acc0 = __builtin_amdgcn_mfma_f32_16x16x32_bf16(avZ[0][3], bw3, acc0, 0, 0, 0);
        acc1 = __builtin_amdgcn_mfma_f32_16x16x32_bf16(avZ[1][3], bw3, acc1, 0, 0, 0);
#pragma unroll
        for (int tg = 0; tg < 2; ++tg) {
            const f32x4 acc = tg ? acc1 : acc0;
            int tokb = Mbase + tg * 16 + quad * 4;
#pragma unroll
            for (int reg = 0; reg < 4; ++reg) {
                size_t tok = (size_t)(tokb + reg);
                float v = acc[reg];
                if (nt < 8)       Qws[tok * 128 + nt * 16 + col0] = v;
                else if (nt < 16) Kws[tok * 128 + (nt - 8) * 16 + col0] = v;
                else if (nt < 24) Vws[tok * 128 + (nt - 16) * 16 + col0] = f2bf(v);
                else if (nt < 26) hqws[tok * 32 + (nt - 24) * 16 + col0] = f2bf(v + (nt == 24 ? b1lo : b1hi));
                else              hkws[tok * 32 + (nt - 26) * 16 + col0] = f2bf(v);
            }
        }
    }
}

// ===== per-bt attention epilogue. grid 512 x 256, 3 blocks/CU ===============
// Arena (43520 B):
//  Qs    [0,16896)      fp32 [32][132]; ThOut alias (P7+)
//  Ks    [16896,33792)  fp32 [32][132]; after P3: Vs bf16 [32][128] @+16896 (8192B),
//                                        Sfrag bf16 @+25344 (8192B)
//  Lg    [33792,38400)  fp32 [32][36]
//  hqL   [38400,40576)  bf16 [32][34]
//  hkL   [40576,42752)  bf16 [32][34]
//  W1e_s [42752,43264) | W2_s [43264,43392) | maskrow [43392,43520)
__global__ __launch_bounds__(256, 3)
void k2_attn(const float* __restrict__ x, const float* __restrict__ edge,
             const float* __restrict__ A_prior, const unsigned char* __restrict__ pad_mask,
             const unsigned short* __restrict__ Wfrag, const float* __restrict__ Wfuse,
             const float* __restrict__ W1, const float* __restrict__ W2,
             const float* __restrict__ b2, const float* __restrict__ gma,
             const float* __restrict__ bta, const float* __restrict__ physw,
             const float* __restrict__ priorw,
             const float* __restrict__ Qws, const float* __restrict__ Kws,
             const unsigned short* __restrict__ Vws,
             const unsigned short* __restrict__ hqws, const unsigned short* __restrict__ hkws,
             float* __restrict__ out)
{
    __shared__ __align__(16) unsigned char arena[43520];
    float* Qs = (float*)arena;
    float* Ks = (float*)(arena + 16896);
    unsigned short* Vs    = (unsigned short*)(arena + 16896);  // post-P3 (Ks dead)
    unsigned short* Sfrag = (unsigned short*)(arena + 25344);  // post-P4
    float* Lg = (float*)(arena + 33792);
    unsigned short* hqL = (unsigned short*)(arena + 38400);
    unsigned short* hkL = (unsigned short*)(arena + 40576);
    float4* W1e_s  = (float4*)(arena + 42752);
    float*  W2_s   = (float*)(arena + 43264);
    float*  maskrow= (float*)(arena + 43392);
    float*  ThOut  = Qs;                                       // alias Qs (P7+), stride 132

    const int tid = threadIdx.x;
    const int bt  = blockIdx.x;
    const int b_ = bt >> 6, t_ = bt & 63;
    const float pw  = physw[0];
    const float rw_ = priorw[0];
    const float b2v = b2[0];

    // ---- early edge/prior loads (P3 operands); prior folded at arrival ----
    const int mp = tid & 15, npg = tid >> 4;
    const int n0 = npg * 2, mA = mp, mB = mp + 16;
    const float wf0 = Wfuse[0], wf1 = Wfuse[1], wf2 = Wfuse[2],
                wf3 = Wfuse[3], wf4 = Wfuse[4];
    float4 e4[2][2];
    float  prv[2][2];
#pragma unroll
    for (int r = 0; r < 2; ++r)
#pragma unroll
        for (int c = 0; c < 2; ++c) {
            int m = c ? mB : mA;
            e4[r][c] = *(const float4*)(edge + (((size_t)bt * 32 + (n0 + r)) * 32 + m) * 4);
            const float* pp = A_prior + (((size_t)bt * 32 + (n0 + r)) * 32 + m) * 5;
            float pr = pp[0]*wf0 + pp[1]*wf1 + pp[2]*wf2 + pp[3]*wf3 + pp[4]*wf4;
            if (!(fabsf(pr) < 1e30f)) pr = 0.f;
            pr = fmaxf(pr, 0.f);
            prv[r][c] = rw_ * __logf(pr + 1e-6f);
        }

    // ---- P0: stage Q,K (fp32->LDS); V -> regs (written to LDS post-P3) ----
    const int row = tid >> 3, vl = (tid & 7) * 8;
    uint4 vreg0, vreg1;
    {
        const int cl = (tid & 7) * 4;
        const size_t gb = ((size_t)bt * 32 + row) * 128;
#pragma unroll
        for (int c = 0; c < 4; ++c) {
            int off = cl + c * 32;
            *(float4*)(Qs + row * 132 + off) = *(const float4*)(Qws + gb + off);
            *(float4*)(Ks + row * 132 + off) = *(const float4*)(Kws + gb + off);
        }
        vreg0 = *(const uint4*)(Vws + gb + vl);
        vreg1 = *(const uint4*)(Vws + gb + vl + 64);
    }
    if (tid < 64) {
        const int r2 = tid & 31;
        const unsigned short* src = (tid < 32 ? hqws : hkws) + ((size_t)bt * 32 + r2) * 32;
        unsigned* dstU = (unsigned*)((tid < 32 ? hqL : hkL) + r2 * 34);
        const uint4* s4 = (const uint4*)src;
#pragma unroll
        for (int i = 0; i < 4; ++i) {
            uint4 w = s4[i];
            dstU[i * 4 + 0] = w.x; dstU[i * 4 + 1] = w.y;
            dstU[i * 4 + 2] = w.z; dstU[i * 4 + 3] = w.w;
        }
    }
    if (tid < 32) {
        int h = tid;
        W1e_s[h] = *(const float4*)(W1 + (size_t)h * 260 + 256);
        W2_s[h]  = W2[h];
        maskrow[h] = pad_mask[b_ * 32 + h] ? 1.f : 0.f;
    }
    __syncthreads();

    // ---- P3: logits; thread covers (n in {n0,n0+1}) x (m in {mA,mB}) ----
    {
        const float* qa = Qs + n0 * 132;
        const float* qb = qa + 132;
        const float* ka = Ks + mA * 132;
        const float* kb = Ks + mB * 132;
        float a00 = 0.f, a01 = 0.f, a10 = 0.f, a11 = 0.f;
        for (int j = 0; j < 128; j += 4) {
            float4 kva = *(const float4*)(ka + j);
            float4 kvb = *(const float4*)(kb + j);
            float4 qva = *(const float4*)(qa + j);
            float4 qvb = *(const float4*)(qb + j);
            a00 = fmaf(qva.x, kva.x, fmaf(qva.y, kva.y, fmaf(qva.z, kva.z, fmaf(qva.w, kva.w, a00))));
            a01 = fmaf(qva.x, kvb.x, fmaf(qva.y, kvb.y, fmaf(qva.z, kvb.z, fmaf(qva.w, kvb.w, a01))));
            a10 = fmaf(qvb.x, kva.x, fmaf(qvb.y, kva.y, fmaf(qvb.z, kva.z, fmaf(qvb.w, kva.w, a10))));
            a11 = fmaf(qvb.x, kvb.x, fmaf(qvb.y, kvb.y, fmaf(qvb.z, kvb.z, fmaf(qvb.w, kvb.w, a11))));
        }
        float pacc[2][2] = {{0.f, 0.f}, {0.f, 0.f}};
#pragma unroll
        for (int h = 0; h < 32; ++h) {
            float4 we = W1e_s[h];
            float w2v = W2_s[h];
            float hq0 = bf2f(hqL[n0 * 34 + h]);
            float hq1 = bf2f(hqL[(n0 + 1) * 34 + h]);
            float hkA = bf2f(hkL[mA * 34 + h]);
            float hkB = bf2f(hkL[mB * 34 + h]);
#pragma unroll
            for (int r = 0; r < 2; ++r) {
                float hqv = r ? hq1 : hq0;
#pragma unroll
                for (int c = 0; c < 2; ++c) {
                    float hkv = c ? hkB : hkA;
                    float4 e = e4[r][c];
                    float he = fmaf(e.x, we.x, fmaf(e.y, we.y, fmaf(e.z, we.z, e.w * we.w)));
                    pacc[r][c] = fmaf(fmaxf(hqv + hkv + he, 0.f), w2v, pacc[r][c]);
                }
            }
        }
        float cont[2][2] = {{a00, a01}, {a10, a11}};
#pragma unroll
        for (int r = 0; r < 2; ++r)
#pragma unroll
            for (int c = 0; c < 2; ++c) {
                int n = n0 + r, m = c ? mB : mA;
                float lg = cont[r][c] * 0.08838834764831845f
                         + pw * (pacc[r][c] + b2v) + prv[r][c];
                if (maskrow[n] != 0.f || maskrow[m] != 0.f) lg = -1e9f;
                Lg[n * 36 + m] = lg;
            }
    }
    __syncthreads();

    // ---- P3.5: V regs -> LDS (Ks region now dead) ----
    *(uint4*)(Vs + row * 128 + vl)      = vreg0;
    *(uint4*)(Vs + row * 128 + vl + 64) = vreg1;

    // ---- P4: wave-parallel softmax (8 lanes per row) ----
    {
        const int n = tid >> 3, q = tid & 7;
        float4 v = *(const float4*)(Lg + n * 36 + q * 4);
        float mx = fmaxf(fmaxf(v.x, v.y), fmaxf(v.z, v.w));
#pragma unroll
        for (int off = 1; off < 8; off <<= 1)
            mx = fmaxf(mx, __shfl_xor(mx, off, 64));
        float ex = __expf(v.x - mx), ey = __expf(v.y - mx),
              ez = __expf(v.z - mx), ew = __expf(v.w - mx);
        float s = (ex + ey) + (ez + ew);
#pragma unroll
        for (int off = 1; off < 8; off <<= 1)
            s += __shfl_xor(s, off, 64);
        float inv = 1.f / s;
        float4 o; o.x = ex * inv; o.y = ey * inv; o.z = ez * inv; o.w = ew * inv;
        *(float4*)(Lg + n * 36 + q * 4) = o;
    }
    __syncthreads();

    const int wv = tid >> 6, lane = tid & 63;
    const int quad = lane >> 4, col0 = lane & 15;
    const int rg = wv & 1, ch = wv >> 1;

    // ---- P6: spatial = alpha @ V (4 rows/thread) -> Sfrag bf16 A-frags ----
    {
        const int d0 = (tid & 31) * 4, ng = tid >> 5;
        const int vks = d0 >> 5, vq = (d0 >> 3) & 3, vj = d0 & 7;
        float sa[4][4] = {};
        for (int m = 0; m < 32; m += 4) {
            float alv[4][4];
#pragma unroll
            for (int r = 0; r < 4; ++r) {
                float4 t = *(const float4*)(Lg + (ng * 4 + r) * 36 + m);
                alv[r][0] = t.x; alv[r][1] = t.y; alv[r][2] = t.z; alv[r][3] = t.w;
            }
#pragma unroll
            for (int mm = 0; mm < 4; ++mm) {
                const unsigned short* vp = Vs + (m + mm) * 128 + d0;
                float v0 = bf2f(vp[0]), v1 = bf2f(vp[1]), v2 = bf2f(vp[2]), v3 = bf2f(vp[3]);
#pragma unroll
                for (int r = 0; r < 4; ++r) {
                    float a = alv[r][mm];
                    sa[r][0] = fmaf(a, v0, sa[r][0]); sa[r][1] = fmaf(a, v1, sa[r][1]);
                    sa[r][2] = fmaf(a, v2, sa[r][2]); sa[r][3] = fmaf(a, v3, sa[r][3]);
                }
            }
        }
#pragma unroll
        for (int r = 0; r < 4; ++r) {
            int nloc = ng * 4 + r;
            int tg = nloc >> 4, nl = nloc & 15;
            unsigned short* sp = Sfrag + ((tg * 4 + vks) * 64 + vq * 16 + nl) * 8 + vj;
            sp[0] = f2bf(sa[r][0]); sp[1] = f2bf(sa[r][1]);
            sp[2] = f2bf(sa[r][2]); sp[3] = f2bf(sa[r][3]);
        }
    }
    __syncthreads();

    // ---- P7: Theta MFMA; frags loaded here (L2-hot 32KB), not held earlier --
    {
        const bf16x8* Wf = (const bf16x8*)Wfrag;
        const f32x4 zero = {0.f, 0.f, 0.f, 0.f};
        f32x4 aT[4] = {zero, zero, zero, zero};
        bf16x8 av0 = *(const bf16x8*)(Sfrag + ((rg * 4 + 0) * 64 + lane) * 8);
        bf16x8 av1 = *(const bf16x8*)(Sfrag + ((rg * 4 + 1) * 64 + lane) * 8);
        bf16x8 av2 = *(const bf16x8*)(Sfrag + ((rg * 4 + 2) * 64 + lane) * 8);
        bf16x8 av3 = *(const bf16x8*)(Sfrag + ((rg * 4 + 3) * 64 + lane) * 8);
#pragma unroll
        for (int nt = 0; nt < 4; ++nt) {
            const int cb = 6144 + ((ch * 4 + nt) * 4) * 64 + lane;
            bf16x8 t0 = Wf[cb + 0 * 64];
            bf16x8 t1 = Wf[cb + 1 * 64];
            bf16x8 t2 = Wf[cb + 2 * 64];
            bf16x8 t3 = Wf[cb + 3 * 64];
            aT[nt] = __builtin_amdgcn_mfma_f32_16x16x32_bf16(av0, t0, aT[nt], 0, 0, 0);
            aT[nt] = __builtin_amdgcn_mfma_f32_16x16x32_bf16(av1, t1, aT[nt], 0, 0, 0);
            aT[nt] = __builtin_amdgcn_mfma_f32_16x16x32_bf16(av2, t2, aT[nt], 0, 0, 0);
            aT[nt] = __builtin_amdgcn_mfma_f32_16x16x32_bf16(av3, t3, aT[nt], 0, 0, 0);
        }
#pragma unroll
        for (int nt = 0; nt < 4; ++nt) {
            int colc = ch * 64 + nt * 16 + col0;
#pragma unroll
            for (int reg = 0; reg < 4; ++reg)
                ThOut[(rg * 16 + quad * 4 + reg) * 132 + colc] = aT[nt][reg];
        }
    }
    __syncthreads();

    // ---- P8: y = x + ThOut; LayerNorm; mask; store (4 rows/thread) ----
    {
        const int d0 = (tid & 31) * 4, ng = tid >> 5;
        float4 g4  = *(const float4*)(gma + d0);
        float4 be4 = *(const float4*)(bta + d0);
#pragma unroll
        for (int r = 0; r < 4; ++r) {
            int nloc = ng * 4 + r;
            const float* xr = x + ((size_t)((b_ * 32 + nloc) * 64 + t_)) * 128 + d0;
            float4 z  = *(const float4*)(xr);
            float4 th = *(const float4*)(ThOut + nloc * 132 + d0);
            float y0 = th.x + z.x, y1 = th.y + z.y, y2 = th.z + z.z, y3 = th.w + z.w;
            float s  = (y0 + y1) + (y2 + y3);
            float s2 = (y0*y0 + y1*y1) + (y2*y2 + y3*y3);
#pragma unroll
            for (int off = 1; off < 32; off <<= 1) {
                s  += __shfl_xor(s,  off, 64);
                s2 += __shfl_xor(s2, off, 64);
            }
            float mu   = s * 0.0078125f;
            float var  = s2 * 0.0078125f - mu * mu;
            float rstd = rsqrtf(var + 1e-5f);
            float msk  = (maskrow[nloc] != 0.f) ? 0.f : 1.f;
            float4 o;
            o.x = ((y0 - mu) * rstd * g4.x + be4.x) * msk;
            o.y = ((y1 - mu) * rstd * g4.y + be4.y) * msk;
            o.z = ((y2 - mu) * rstd * g4.z + be4.z) * msk;
            o.w = ((y3 - mu) * rstd * g4.w + be4.w) * msk;
            *(float4*)(out + ((size_t)((b_ * 32 + nloc) * 64 + t_)) * 128 + d0) = o;
        }
    }
}

// ===========================================================================
// ===== R9 FALLBACK PATH (used only if ws_size is too small) ================
// ===========================================================================
__global__ __launch_bounds__(256) void k0a_pack_w(
    const float* __restrict__ Wq, const float* __restrict__ Wk,
    const float* __restrict__ Wv, const float* __restrict__ Theta,
    unsigned short* __restrict__ Wfrag)
{
    int gid = blockIdx.x * 256 + threadIdx.x;      // 0..8191
    int g = gid >> 11, c = gid & 2047;
    int ntk = c >> 6, lane = c & 63;
    int i = (ntk >> 2) * 16 + (lane & 15);
    int j = (ntk & 3) * 32 + (lane >> 4) * 8;
    const float* src = (g == 0 ? Wq : g == 1 ? Wk : g == 2 ? Wv : Theta) + (size_t)i * 128 + j;
    float4 a = *(const float4*)(src);
    float4 b = *(const float4*)(src + 4);
    uint4 pk;
    pk.x = pack2(a.x, a.y); pk.y = pack2(a.z, a.w);
    pk.z = pack2(b.x, b.y); pk.w = pack2(b.z, b.w);
    *(uint4*)(Wfrag + (size_t)gid * 8) = pk;
}

__global__ __launch_bounds__(256, 1) void k0b_compose(
    const float* __restrict__ Wq, const float* __restrict__ Wk,
    const float* __restrict__ W1, unsigned short* __restrict__ Wfrag)
{
    __shared__ __align__(16) float Ws[128 * 132];
    __shared__ __align__(16) float W1s[8 * 128];
    const int tid = threadIdx.x;
    const int mat   = blockIdx.x & 1;
    const int hbase = (blockIdx.x >> 1) * 8;
    const float* Wsel = mat ? Wk : Wq;
#pragma unroll
    for (int q = 0; q < 16; ++q) {
        int f = tid + 256 * q;
        int i = f >> 5, c4 = (f & 31) * 4;
        *(float4*)(Ws + i * 132 + c4) = *(const float4*)(Wsel + (size_t)i * 128 + c4);
    }
#pragma unroll
    for (int q = 0; q < 4; ++q) {
        int f = tid + 256 * q;
        int hl = f >> 7, i = f & 127;
        W1s[hl * 128 + i] = W1[(size_t)(hbase + hl) * 260 + mat * 128 + i];
    }
    __syncthreads();
    const int hl = tid >> 5;
    const int h  = hbase + hl;
    const int j0 = (tid & 31) * 4;
    float4 acc = {0.f, 0.f, 0.f, 0.f};
    for (int i = 0; i < 128; ++i) {
        float c = W1s[hl * 128 + i];
        float4 w = *(const float4*)(Ws + i * 132 + j0);
        acc.x = fmaf(c, w.x, acc.x); acc.y = fmaf(c, w.y, acc.y);
        acc.z = fmaf(c, w.z, acc.z); acc.w = fmaf(c, w.w, acc.w);
    }
    const int nt = h >> 4;
    const unsigned base = 65536u + (unsigned)mat * 4096u;   // shorts
    float av[4] = {acc.x, acc.y, acc.z, acc.w};
#pragma unroll
    for (int jj = 0; jj < 4; ++jj) {
        int j = j0 + jj;
        int lane = (h & 15) | (((j >> 3) & 3) << 4);
        int ks = j >> 5, vj = j & 7;
        Wfrag[base + (unsigned)((nt * 4 + ks) * 64 + lane) * 8 + vj] = f2bf(av[jj]);
    }
}

__global__ __launch_bounds__(256, 4)
void gnn_fused(const float* __restrict__ x,
               const float* __restrict__ edge,
               const float* __restrict__ A_prior,
               const unsigned char* __restrict__ pad_mask,
               const unsigned short* __restrict__ Wfrag,
               const float* __restrict__ Wfuse,
               const float* __restrict__ W1,
               const float* __restrict__ b1,
               const float* __restrict__ W2,
               const float* __restrict__ b2,
               const float* __restrict__ gma,
               const float* __restrict__ bta,
               const float* __restrict__ physw,
               const float* __restrict__ priorw,
               float* __restrict__ out)
{
    __shared__ __align__(16) unsigned char arena[39648];
    unsigned short* Zfrag = (unsigned short*)(arena);
    float*          Qs    = (float*)(arena);
    unsigned short* Sfrag = (unsigned short*)(arena);
    float*          Ks    = (float*)(arena + 8192);
    unsigned short* Vfrag = (unsigned short*)(arena + 25088);
    float*          ThOut = (float*)(arena + 25088);
    float*          Lg    = (float*)(arena + 33280);
    unsigned short* hqT   = (unsigned short*)(arena + 35392);
    unsigned short* hks   = (unsigned short*)(arena + 36544);
    float4* W1e_s  = (float4*)(arena + 38720);
    float*  W2_s   = (float*)(arena + 39232);
    float*  b1s    = (float*)(arena + 39360);
    float*  maskrow= (float*)(arena + 39488);
    float*  Wf_s   = (float*)(arena + 39616);

    const int tid  = threadIdx.x;
    const int bt   = blockIdx.x >> 1;
    const int half = blockIdx.x & 1;
    const int b_ = bt >> 6, t_ = bt & 63;
    const float pw  = physw[0];
    const float rw_ = priorw[0];
    const float b2v = b2[0];

    const int m3 = tid & 31, n23 = tid >> 5;
    float4 e4[2];
    float pr5[2][5];
#pragma unroll
    for (int r = 0; r < 2; ++r) {
        int ng = half * 16 + n23 * 2 + r;
        e4[r] = *(const float4*)(edge + (((size_t)bt * 32 + ng) * 32 + m3) * 4);
        size_t pb = (((size_t)bt * 32 + ng) * 32 + m3) * 5;
#pragma unroll
        for (int j5 = 0; j5 < 5; ++j5) pr5[r][j5] = A_prior[pb + j5];
    }
#pragma unroll
    for (int it = 0; it < 2; ++it) {
        int f = tid + 256 * it;
        int lane9 = f & 63, ntk = f >> 6;
        int mm = lane9 & 15, qq = lane9 >> 4;
        int n = (ntk >> 2) * 16 + mm;
        int d = (ntk & 3) * 32 + qq * 8;
        const float* xr = x + ((size_t)((b_ * 32 + n) * 64 + t_)) * 128 + d;
        float4 a = *(const float4*)(xr);
        float4 b = *(const float4*)(xr + 4);
        uint4 pk;
        pk.x = pack2(a.x, a.y); pk.y = pack2(a.z, a.w);
        pk.z = pack2(b.x, b.y); pk.w = pack2(b.z, b.w);
        *(uint4*)(Zfrag + f * 8) = pk;
    }
    if (tid < 32) {
        int h = tid;
        W1e_s[h] = *(const float4*)(W1 + (size_t)h * 260 + 256);
        W2_s[h]  = W2[h];
        b1s[h]   = b1[h];
        maskrow[h] = pad_mask[b_ * 32 + h] ? 1.f : 0.f;
        if (h < 5) Wf_s[h] = Wfuse[h];
    }
    __syncthreads();

    const int wv = tid >> 6, lane = tid & 63;
    const int quad = lane >> 4, col0 = lane & 15;
    const bf16x8* Wf = (const bf16x8*)Wfrag;

    {
        const int Mtk = wv & 1;
        const int ng4 = (wv >> 1) * 4;
        f32x4 zero = {0.f, 0.f, 0.f, 0.f};
        f32x4 aK[4] = {zero, zero, zero, zero};
        f32x4 aV[4] = {zero, zero, zero, zero};
        f32x4 aQ[2] = {zero, zero};
        f32x4 aHq = zero, aHk = zero;
#pragma unroll
        for (int ks = 0; ks < 4; ++ks) {
            bf16x8 avK = *(const bf16x8*)(Zfrag + ((Mtk * 4 + ks) * 64 + lane) * 8);
            bf16x8 avQ = *(const bf16x8*)(Zfrag + ((half * 4 + ks) * 64 + lane) * 8);
#pragma unroll
            for (int nt = 0; nt < 4; ++nt) {
                int bi = ((ng4 + nt) * 4 + ks) * 64 + lane;
                aK[nt] = __builtin_amdgcn_mfma_f32_16x16x32_bf16(avK, Wf[bi + 2048], aK[nt], 0, 0, 0);
                aV[nt] = __builtin_amdgcn_mfma_f32_16x16x32_bf16(avK, Wf[bi + 4096], aV[nt], 0, 0, 0);
            }
#pragma unroll
            for (int nt = 0; nt < 2; ++nt) {
                int bq = ((wv * 2 + nt) * 4 + ks) * 64 + lane;
                aQ[nt] = __builtin_amdgcn_mfma_f32_16x16x32_bf16(avQ, Wf[bq], aQ[nt], 0, 0, 0);
            }
            if (wv < 2)
                aHq = __builtin_amdgcn_mfma_f32_16x16x32_bf16(avQ, Wf[8192 + (wv * 4 + ks) * 64 + lane], aHq, 0, 0, 0);
            aHk = __builtin_amdgcn_mfma_f32_16x16x32_bf16(avK, Wf[8704 + ((wv >> 1) * 4 + ks) * 64 + lane], aHk, 0, 0, 0);
        }
        __syncthreads();
#pragma unroll
        for (int nt = 0; nt < 4; ++nt) {
            int colc = (ng4 + nt) * 16 + col0;
            int vks = colc >> 5, vq = (colc >> 3) & 3, vj = colc & 7;
#pragma unroll
            for (int reg = 0; reg < 4; ++reg) {
                int rrow = Mtk * 16 + quad * 4 + reg;
                Ks[rrow * 132 + colc] = aK[nt][reg];
                int idx = (Mtk * 4 + vks) * 64 + vq * 16 + (quad * 4 + reg);
                Vfrag[idx * 8 + vj] = f2bf(aV[nt][reg]);
            }
        }
#pragma unroll
        for (int nt = 0; nt < 2; ++nt) {
            int colc = (wv * 2 + nt) * 16 + col0;
#pragma unroll
            for (int reg = 0; reg < 4; ++reg)
                Qs[(quad * 4 + reg) * 128 + colc] = aQ[nt][reg];
        }
        if (wv < 2) {
            int h = wv * 16 + col0;
#pragma unroll
            for (int reg = 0; reg < 4; ++reg)
                hqT[h * 18 + (quad * 4 + reg)] = f2bf(aHq[reg] + b1s[h]);
        }
        {
            int h = (wv >> 1) * 16 + col0;
#pragma unroll
            for (int reg = 0; reg < 4; ++reg)
                hks[(Mtk * 16 + quad * 4 + reg) * 34 + h] = f2bf(aHk[reg]);
        }
    }
    __syncthreads();

    {
        const int m = m3, n2 = n23;
        const float* krow = Ks + m * 132;
        const float* q0 = Qs + (n2 * 2) * 128;
        const float* q1 = Qs + (n2 * 2 + 1) * 128;
        float acc0 = 0.f, acc1 = 0.f;
        for (int j = 0; j < 128; j += 4) {
            float4 k4 = *(const float4*)(krow + j);
            float4 qa = *(const float4*)(q0 + j);
            float4 qb = *(const float4*)(q1 + j);
            acc0 = fmaf(qa.x, k4.x, fmaf(qa.y, k4.y, fmaf(qa.z, k4.z, fmaf(qa.w, k4.w, acc0))));
            acc1 = fmaf(qb.x, k4.x, fmaf(qb.y, k4.y, fmaf(qb.z, k4.z, fmaf(qb.w, k4.w, acc1))));
        }
        float pacc[2] = {0.f, 0.f};
        for (int h = 0; h < 32; ++h) {
            float4 we = W1e_s[h];
            float w2v = W2_s[h];
            float hkv = bf2f(hks[m * 34 + h]);
            float hq0 = bf2f(hqT[h * 18 + n2 * 2]);
            float hq1 = bf2f(hqT[h * 18 + n2 * 2 + 1]);
            float he0 = fmaf(e4[0].x, we.x, fmaf(e4[0].y, we.y, fmaf(e4[0].z, we.z, e4[0].w * we.w)));
            float he1 = fmaf(e4[1].x, we.x, fmaf(e4[1].y, we.y, fmaf(e4[1].z, we.z, e4[1].w * we.w)));
            pacc[0] = fmaf(fmaxf(hq0 + hkv + he0, 0.f), w2v, pacc[0]);
            pacc[1] = fmaf(fmaxf(hq1 + hkv + he1, 0.f), w2v, pacc[1]);
        }
        float cont[2] = {acc0, acc1};
#pragma unroll
        for (int r = 0; r < 2; ++r) {
            int nloc = n2 * 2 + r, ng = half * 16 + nloc;
            float pr = pr5[r][0]*Wf_s[0] + pr5[r][1]*Wf_s[1] + pr5[r][2]*Wf_s[2]
                     + pr5[r][3]*Wf_s[3] + pr5[r][4]*Wf_s[4];
            if (!(fabsf(pr) < 1e30f)) pr = 0.f;
            pr = fmaxf(pr, 0.f);
            float lg = cont[r] * 0.08838834764831845f
                     + pw * (pacc[r] + b2v) + rw_ * __logf(pr + 1e-6f);
            if (maskrow[ng] != 0.f || maskrow[m] != 0.f) lg = -1e9f;
            Lg[nloc * 33 + m] = lg;
        }
    }
    __syncthreads();

    if (tid < 16) {
        const int n = tid;
        float mx = -3.4e38f;
        for (int m2 = 0; m2 < 32; ++m2) mx = fmaxf(mx, Lg[n * 33 + m2]);
        float s = 0.f;
        for (int m2 = 0; m2 < 32; ++m2) {
            float e = __expf(Lg[n * 33 + m2] - mx);
            Lg[n * 33 + m2] = e; s += e;
        }
        float inv = 1.f / s;
        for (int m2 = 0; m2 < 32; ++m2) Lg[n * 33 + m2] *= inv;
    }
    __syncthreads();

    {
        const int d0 = (tid & 31) * 4, nl0 = (tid >> 5) * 2;
        const int vks = d0 >> 5, vq = (d0 >> 3) & 3, vj = d0 & 7;
        float sa[2][4] = {{0,0,0,0},{0,0,0,0}};
        for (int m = 0; m < 32; ++m) {
            int idx = ((m >> 4) * 4 + vks) * 64 + vq * 16 + (m & 15);
            const unsigned short* vp = Vfrag + idx * 8 + vj;
            float v0 = bf2f(vp[0]), v1 = bf2f(vp[1]), v2 = bf2f(vp[2]), v3 = bf2f(vp[3]);
            float a0 = Lg[nl0 * 33 + m], a1 = Lg[(nl0 + 1) * 33 + m];
            sa[0][0]=fmaf(a0,v0,sa[0][0]); sa[0][1]=fmaf(a0,v1,sa[0][1]);
            sa[0][2]=fmaf(a0,v2,sa[0][2]); sa[0][3]=fmaf(a0,v3,sa[0][3]);
            sa[1][0]=fmaf(a1,v0,sa[1][0]); sa[1][1]=fmaf(a1,v1,sa[1][1]);
            sa[1][2]=fmaf(a1,v2,sa[1][2]); sa[1][3]=fmaf(a1,v3,sa[1][3]);
        }
#pragma unroll
        for (int r = 0; r < 2; ++r) {
            int nloc = nl0 + r;
            unsigned short* sp = Sfrag + (vks * 64 + vq * 16 + nloc) * 8 + vj;
            sp[0] = f2bf(sa[r][0]); sp[1] = f2bf(sa[r][1]);
            sp[2] = f2bf(sa[r][2]); sp[3] = f2bf(sa[r][3]);
        }
    }
    __syncthreads();

    {
        f32x4 aT[2] = {{0.f,0.f,0.f,0.f},{0.f,0.f,0.f,0.f}};
#pragma unroll
        for (int ks = 0; ks < 4; ++ks) {
            bf16x8 av = *(const bf16x8*)(Sfrag + (ks * 64 + lane) * 8);
#pragma unroll
            for (int nt = 0; nt < 2; ++nt)
                aT[nt] = __builtin_amdgcn_mfma_f32_16x16x32_bf16(
                    av, Wf[6144 + ((wv * 2 + nt) * 4 + ks) * 64 + lane], aT[nt], 0, 0, 0);
        }
#pragma unroll
        for (int nt = 0; nt < 2; ++nt) {
            int colc = (wv * 2 + nt) * 16 + col0;
#pragma unroll
            for (int reg = 0; reg < 4; ++reg)
                ThOut[(quad * 4 + reg) * 128 + colc] = aT[nt][reg];
        }
    }
    __syncthreads();

    {
        const int d0 = (tid & 31) * 4, n2 = tid >> 5;
        float4 g4  = *(const float4*)(gma + d0);
        float4 be4 = *(const float4*)(bta + d0);
#pragma unroll
        for (int r = 0; r < 2; ++r) {
            int nloc = n2 * 2 + r, ng = half * 16 + nloc;
            const float* xr = x + ((size_t)((b_ * 32 + ng) * 64 + t_)) * 128 + d0;
            float4 z  = *(const float4*)(xr);
            float4 th = *(const float4*)(ThOut + nloc * 128 + d0);
            float y0 = th.x + z.x, y1 = th.y + z.y, y2 = th.z + z.z, y3 = th.w + z.w;
            float s  = (y0 + y1) + (y2 + y3);
            float s2 = (y0*y0 + y1*y1) + (y2*y2 + y3*y3);
#pragma unroll
            for (int off = 1; off < 32; off <<= 1) {
                s  += __shfl_xor(s,  off, 64);
                s2 += __shfl_xor(s2, off, 64);
            }
            float mu   = s * 0.0078125f;
            float var  = s2 * 0.0078125f - mu * mu;
            float rstd = rsqrtf(var + 1e-5f);
            float msk  = (maskrow[ng] != 0.f) ? 0.f : 1.f;
            float4 o;
            o.x = ((y0 - mu) * rstd * g4.x + be4.x) * msk;
            o.y = ((y1 - mu) * rstd * g4.y + be4.y) * msk;
            o.z = ((y2 - mu) * rstd * g4.z + be4.z) * msk;
            o.w = ((y3 - mu) * rstd * g4.w + be4.w) * msk;
            *(float4*)(out + ((size_t)((b_ * 32 + ng) * 64 + t_)) * 128 + d0) = o;
        }
    }
}

// ===========================================================================
extern "C" void kernel_launch(void* const* d_in, const int* in_sizes, int n_in,
                              void* d_out, int out_size, void* d_ws, size_t ws_size,
                              hipStream_t stream) {
    const float* x        = (const float*)d_in[0];
    const float* edge     = (const float*)d_in[1];
    const float* A_prior  = (const float*)d_in[2];
    const unsigned char* pad_mask = (const unsigned char*)d_in[3];
    const float* Wq       = (const float*)d_in[4];
    const float* Wk       = (const float*)d_in[5];
    const float* Wv       = (const float*)d_in[6];
    const float* Theta    = (const float*)d_in[7];
    const float* Wfuse    = (const float*)d_in[8];
    const float* W1       = (const float*)d_in[9];
    const float* b1       = (const float*)d_in[10];
    const float* W2       = (const float*)d_in[11];
    const float* b2       = (const float*)d_in[12];
    const float* gma      = (const float*)d_in[13];
    const float* bta      = (const float*)d_in[14];
    const float* physw    = (const float*)d_in[15];
    const float* priorw   = (const float*)d_in[16];
    float* out = (float*)d_out;

    unsigned short* Wfrag = (unsigned short*)d_ws;   // 147456 B

    // workspace layout (fast path):
    //   [0,147456)            Wfrag
    //   +8388608              Qws   fp32 [16384][128]
    //   +8388608              Kws   fp32 [16384][128]
    //   +4194304              Vws   bf16 [16384][128]
    //   +1048576              hqws  bf16 [16384][32]
    //   +1048576              hkws  bf16 [16384][32]
    const size_t NEED = 147456ull + 8388608ull * 2 + 4194304ull + 1048576ull * 2; // 23216128

    if (ws_size >= NEED) {
        float* Qws = (float*)((char*)d_ws + 147456);
        float* Kws = (float*)((char*)d_ws + 147456 + 8388608ull);
        unsigned short* Vws  = (unsigned short*)((char*)d_ws + 147456 + 16777216ull);
        unsigned short* hqws = (unsigned short*)((char*)d_ws + 147456 + 16777216ull + 4194304ull);
        unsigned short* hkws = hqws + (size_t)16384 * 32;

        k0_prep<<<dim3(64), dim3(256), 0, stream>>>(Wq, Wk, Wv, Theta, W1, Wfrag);
        k1_proj<<<dim3(512), dim3(256), 0, stream>>>(x, Wfrag, b1, Qws, Kws, Vws, hqws, hkws);
        k2_attn<<<dim3(512), dim3(256), 0, stream>>>(
            x, edge, A_prior, pad_mask, Wfrag, Wfuse, W1, W2, b2,
            gma, bta, physw, priorw, Qws, Kws, Vws, hqws, hkws, out);
    } else {
        // R9 fallback
        k0a_pack_w<<<dim3(32), dim3(256), 0, stream>>>(Wq, Wk, Wv, Theta, Wfrag);
        k0b_compose<<<dim3(8), dim3(256), 0, stream>>>(Wq, Wk, W1, Wfrag);
        gnn_fused<<<dim3(1024), dim3(256), 0, stream>>>(
            x, edge, A_prior, pad_mask, Wfrag, Wfuse,
            W1, b1, W2, b2, gma, bta, physw, priorw, out);
    }
}

// Round 4
// 278.930 us; speedup vs baseline: 1.1699x; 1.1699x over previous
//
#include <hip/hip_runtime.h>

// B=8, N=32, T=64, D=128, E=4, H=32, BT=512
// R13: CU-resident weights, zero round-trips. Evidence: four structurally
// different kernels all ran at bytes/2.9TB/s (dur tracks hbm_bytes exactly);
// occupancy was irrelevant (R9 40% == R11 21%). Irreducible bytes ~45MB vs
// 520-650MB measured => kill traffic, not latency. Design: grid 256 (1
// block/CU), 150.5KB LDS = Wq|Wk|Wv frags (98KB, staged ONCE) + arena
// (52KB); each block runs 2 bt's fully fused: projection MFMA -> logits ->
// softmax -> spatial -> Theta MFMA -> LN. Cq/Ck+Theta frags (48KB) stay
// L2-resident-global. No Qws/Kws/Vws workspace. All phase code verbatim
// from validated rounds (proj=k1, P3/P4=R12, P6/P7=R11-style thf prefetch).

typedef __bf16 bf16x8 __attribute__((ext_vector_type(8)));
typedef float  f32x4  __attribute__((ext_vector_type(4)));

static __device__ __forceinline__ unsigned short f2bf(float f) {
    unsigned u = __float_as_uint(f);
    u += 0x7fffu + ((u >> 16) & 1u);        // RNE
    return (unsigned short)(u >> 16);
}
static __device__ __forceinline__ float bf2f(unsigned short u) {
    return __uint_as_float(((unsigned)u) << 16);
}
static __device__ __forceinline__ unsigned pack2(float a, float b) {
    return (unsigned)f2bf(a) | ((unsigned)f2bf(b) << 16);
}

// ---------------------------------------------------------------------------
// Wfrag (16B chunks): [0,2048) Wq | [2048,4096) Wk | [4096,6144) Wv |
// [6144,8192) Theta | chunk 8192+: Cq=W1q@Wq (512), chunk 8704+: Ck=W1k@Wk (512).
// B-frag chunk (nt*4+ks)*64+lane holds B[k=j][n]: n = nt*16+(lane&15),
// j = ks*32+(lane>>4)*8 + (0..7).
// ---------------------------------------------------------------------------

__global__ __launch_bounds__(256) void k0_prep(
    const float* __restrict__ Wq, const float* __restrict__ Wk,
    const float* __restrict__ Wv, const float* __restrict__ Theta,
    const float* __restrict__ W1, unsigned short* __restrict__ Wfrag)
{
    const int tid = threadIdx.x;
    if (blockIdx.x < 32) {
        int gid = blockIdx.x * 256 + tid;      // 0..8191
        int g = gid >> 11, c = gid & 2047;
        int ntk = c >> 6, lane = c & 63;
        int i = (ntk >> 2) * 16 + (lane & 15);
        int j = (ntk & 3) * 32 + (lane >> 4) * 8;
        const float* src = (g == 0 ? Wq : g == 1 ? Wk : g == 2 ? Wv : Theta) + (size_t)i * 128 + j;
        float4 a = *(const float4*)(src);
        float4 b = *(const float4*)(src + 4);
        uint4 pk;
        pk.x = pack2(a.x, a.y); pk.y = pack2(a.z, a.w);
        pk.z = pack2(b.x, b.y); pk.w = pack2(b.z, b.w);
        *(uint4*)(Wfrag + (size_t)gid * 8) = pk;
    } else {
        // compose Cq = W1q@Wq, Ck = W1k@Wk
        int b2 = blockIdx.x - 32;              // 0..31
        int mat = b2 & 1;
        int hbase = (b2 >> 1) * 2;
        int hl = tid >> 7, col = tid & 127;
        int h = hbase + hl;
        const float* Wsel = mat ? Wk : Wq;
        const float* w1r = W1 + (size_t)h * 260 + mat * 128;
        float acc = 0.f;
        for (int i = 0; i < 128; ++i)
            acc = fmaf(w1r[i], Wsel[(size_t)i * 128 + col], acc);
        int nt = h >> 4;
        unsigned base = 65536u + (unsigned)mat * 4096u;   // shorts
        int lane = (h & 15) | (((col >> 3) & 3) << 4);
        int ks = col >> 5, vj = col & 7;
        Wfrag[base + (unsigned)((nt * 4 + ks) * 64 + lane) * 8 + vj] = f2bf(acc);
    }
}

// ===== fully fused: grid 256 x 256 threads, 1 block/CU, 2 bt per block =====
// LDS: WL 98304 B (Wq|Wk|Wv B-frags, staged once) + arena 52224 B = 150528 B.
// Arena: Qs[32][132] f32 @0 (Zfrag alias pre-proj, ThOut alias post-P7)
//        Ks[32][132] f32 @16896 (Sfrag alias post-P3)
//        Vs[32][136] bf16 @33792 | Lg[32][36] f32 @42496
//        hqL[32][34] bf16 @47104 | hkL[32][34] bf16 @49280
//        W1e_s @51456 | W2_s @51968 | maskrow @52096
__global__ __launch_bounds__(256, 1)
void gnn_all(const float* __restrict__ x, const float* __restrict__ edge,
             const float* __restrict__ A_prior, const unsigned char* __restrict__ pad_mask,
             const unsigned short* __restrict__ Wfrag, const float* __restrict__ Wfuse,
             const float* __restrict__ W1, const float* __restrict__ b1,
             const float* __restrict__ W2, const float* __restrict__ b2,
             const float* __restrict__ gma, const float* __restrict__ bta,
             const float* __restrict__ physw, const float* __restrict__ priorw,
             float* __restrict__ out)
{
    __shared__ __align__(16) unsigned short WL[6144 * 8];    // 98304 B
    __shared__ __align__(16) unsigned char arena[52224];
    float*          Qs    = (float*)arena;
    unsigned short* Zfrag = (unsigned short*)arena;           // pre-projection
    float*          ThOut = Qs;                               // post-P7, stride 132
    float*          Ks    = (float*)(arena + 16896);
    unsigned short* Sfrag = (unsigned short*)(arena + 16896); // post-P3
    unsigned short* Vs    = (unsigned short*)(arena + 33792); // [32][136]
    float*          Lg    = (float*)(arena + 42496);          // [32][36]
    unsigned short* hqL   = (unsigned short*)(arena + 47104);
    unsigned short* hkL   = (unsigned short*)(arena + 49280);
    float4*         W1e_s = (float4*)(arena + 51456);
    float*          W2_s  = (float*)(arena + 51968);
    float*          maskrow = (float*)(arena + 52096);

    const int tid = threadIdx.x;
    const int blk = blockIdx.x;
    const int b_  = blk >> 5;
    const int t0  = (blk & 31) * 2;

    const float pw  = physw[0];
    const float rw_ = priorw[0];
    const float b2v = b2[0];
    const float wf0 = Wfuse[0], wf1 = Wfuse[1], wf2 = Wfuse[2],
                wf3 = Wfuse[3], wf4 = Wfuse[4];

    const int wv = tid >> 6, lane = tid & 63;
    const int quad = lane >> 4, col0 = lane & 15;
    const float b1lo = b1[col0], b1hi = b1[16 + col0];
    const int d0p = (tid & 31) * 4, ngp = tid >> 5;           // P6/P8 mapping
    const float4 g4  = *(const float4*)(gma + d0p);
    const float4 be4 = *(const float4*)(bta + d0p);

    // ---- stage Wq|Wk|Wv B-frags once (98 KB) + small weights ----
    {
        const uint4* src = (const uint4*)Wfrag;
        uint4* dst = (uint4*)WL;
#pragma unroll
        for (int i = 0; i < 24; ++i) dst[tid + 256 * i] = src[tid + 256 * i];
    }
    if (tid < 32) {
        W1e_s[tid] = *(const float4*)(W1 + (size_t)tid * 260 + 256);
        W2_s[tid]  = W2[tid];
        maskrow[tid] = pad_mask[b_ * 32 + tid] ? 1.f : 0.f;
    }
    __syncthreads();

    const bf16x8* WfG = (const bf16x8*)Wfrag;    // global: Theta + Cq/Ck
    const bf16x8* WLv = (const bf16x8*)WL;       // LDS: Wq|Wk|Wv

    for (int itbt = 0; itbt < 2; ++itbt) {
        const int bt = blk * 2 + itbt;           // b_ = bt>>6 (invariant), t_:
        const int t_ = t0 + itbt;

        // ---- early edge/prior loads; prior folded at arrival ----
        const int mp = tid & 15, npg = tid >> 4;
        const int n0 = npg * 2, mA = mp, mB = mp + 16;
        float4 e4[2][2];
        float  prv[2][2];
#pragma unroll
        for (int r = 0; r < 2; ++r)
#pragma unroll
            for (int c = 0; c < 2; ++c) {
                int m = c ? mB : mA;
                e4[r][c] = *(const float4*)(edge + (((size_t)bt * 32 + (n0 + r)) * 32 + m) * 4);
                const float* pp = A_prior + (((size_t)bt * 32 + (n0 + r)) * 32 + m) * 5;
                float pr = pp[0]*wf0 + pp[1]*wf1 + pp[2]*wf2 + pp[3]*wf3 + pp[4]*wf4;
                if (!(fabsf(pr) < 1e30f)) pr = 0.f;
                pr = fmaxf(pr, 0.f);
                prv[r][c] = rw_ * __logf(pr + 1e-6f);
            }

        // ---- Z staging: pack x -> bf16 A-frags (512 chunks in Qs region) ----
#pragma unroll
        for (int it2 = 0; it2 < 2; ++it2) {
            int f = tid + 256 * it2;                // chunk 0..511
            int lane9 = f & 63, tk = f >> 6;        // tk 0..7
            int nl = (tk >> 2) * 16 + (lane9 & 15); // token 0..31
            int d  = (tk & 3) * 32 + (lane9 >> 4) * 8;
            const float* xr = x + ((size_t)((b_ * 32 + nl) * 64 + t_)) * 128 + d;
            float4 a = *(const float4*)(xr);
            float4 b = *(const float4*)(xr + 4);
            uint4 pk;
            pk.x = pack2(a.x, a.y); pk.y = pack2(a.z, a.w);
            pk.z = pack2(b.x, b.y); pk.w = pack2(b.z, b.w);
            *(uint4*)(Zfrag + f * 8) = pk;
        }
        __syncthreads();

        // ---- A-frags to regs; barrier before Qs overwrite ----
        bf16x8 avZ[2][4];
#pragma unroll
        for (int tg = 0; tg < 2; ++tg)
#pragma unroll
            for (int ks = 0; ks < 4; ++ks)
                avZ[tg][ks] = *(const bf16x8*)(Zfrag + ((tg * 4 + ks) * 64 + lane) * 8);
        __syncthreads();

        // ---- projection: per wave nt set {wv, wv+4, ..., wv+24} ----
        const f32x4 zero = {0.f, 0.f, 0.f, 0.f};
#pragma unroll
        for (int k7 = 0; k7 < 7; ++k7) {
            const int nt = wv + k7 * 4;             // wave-uniform
            bf16x8 bw0, bw1, bw2, bw3;
            if (nt < 24) {
                const int cb = nt * 256 + lane;
                bw0 = WLv[cb];       bw1 = WLv[cb + 64];
                bw2 = WLv[cb + 128]; bw3 = WLv[cb + 192];
            } else {
                const int cb = 8192 + (nt - 24) * 256 + lane;
                bw0 = WfG[cb];       bw1 = WfG[cb + 64];
                bw2 = WfG[cb + 128]; bw3 = WfG[cb + 192];
            }
            f32x4 acc0 = zero, acc1 = zero;
            acc0 = __builtin_amdgcn_mfma_f32_16x16x32_bf16(avZ[0][0], bw0, acc0, 0, 0, 0);
            acc1 = __builtin_amdgcn_mfma_f32_16x16x32_bf16(avZ[1][0], bw0, acc1, 0, 0, 0);
            acc0 = __builtin_amdgcn_mfma_f32_16x16x32_bf16(avZ[0][1], bw1, acc0, 0, 0, 0);
            acc1 = __builtin_amdgcn_mfma_f32_16x16x32_bf16(avZ[1][1], bw1, acc1, 0, 0, 0);
            acc0 = __builtin_amdgcn_mfma_f32_16x16x32_bf16(avZ[0][2], bw2, acc0, 0, 0, 0);
            acc1 = __builtin_amdgcn_mfma_f32_16x16x32_bf16(avZ[1][2], bw2, acc1, 0, 0, 0);
            acc0 = __builtin_amdgcn_mfma_f32_16x16x32_bf16(avZ[0][3], bw3, acc0, 0, 0, 0);
            acc1 = __builtin_amdgcn_mfma_f32_16x16x32_bf16(avZ[1][3], bw3, acc1, 0, 0, 0);
#pragma unroll
            for (int tg = 0; tg < 2; ++tg) {
                const f32x4 acc = tg ? acc1 : acc0;
                const int tokb = tg * 16 + quad * 4;
#pragma unroll
                for (int reg = 0; reg < 4; ++reg) {
                    int tok = tokb + reg;
                    float v = acc[reg];
                    if (nt < 8)       Qs[tok * 132 + nt * 16 + col0] = v;
                    else if (nt < 16) Ks[tok * 132 + (nt - 8) * 16 + col0] = v;
                    else if (nt < 24) Vs[tok * 136 + (nt - 16) * 16 + col0] = f2bf(v);
                    else if (nt < 26) hqL[tok * 34 + (nt - 24) * 16 + col0] = f2bf(v + (nt == 24 ? b1lo : b1hi));
                    else              hkL[tok * 34 + (nt - 26) * 16 + col0] = f2bf(v);
                }
            }
        }
        __syncthreads();

        // ---- P3: logits (fp32 VALU QK^T + phys MLP + prior) -> Lg ----
        {
            const float* qa = Qs + n0 * 132;
            const float* qb = qa + 132;
            const float* ka = Ks + mA * 132;
            const float* kb = Ks + mB * 132;
            float a00 = 0.f, a01 = 0.f, a10 = 0.f, a11 = 0.f;
            for (int j = 0; j < 128; j += 4) {
                float4 kva = *(const float4*)(ka + j);
                float4 kvb = *(const float4*)(kb + j);
                float4 qva = *(const float4*)(qa + j);
                float4 qvb = *(const float4*)(qb + j);
                a00 = fmaf(qva.x, kva.x, fmaf(qva.y, kva.y, fmaf(qva.z, kva.z, fmaf(qva.w, kva.w, a00))));
                a01 = fmaf(qva.x, kvb.x, fmaf(qva.y, kvb.y, fmaf(qva.z, kvb.z, fmaf(qva.w, kvb.w, a01))));
                a10 = fmaf(qvb.x, kva.x, fmaf(qvb.y, kva.y, fmaf(qvb.z, kva.z, fmaf(qvb.w, kva.w, a10))));
                a11 = fmaf(qvb.x, kvb.x, fmaf(qvb.y, kvb.y, fmaf(qvb.z, kvb.z, fmaf(qvb.w, kvb.w, a11))));
            }
            float pacc[2][2] = {{0.f, 0.f}, {0.f, 0.f}};
#pragma unroll
            for (int h = 0; h < 32; ++h) {
                float4 we = W1e_s[h];
                float w2v = W2_s[h];
                float hq0 = bf2f(hqL[n0 * 34 + h]);
                float hq1 = bf2f(hqL[(n0 + 1) * 34 + h]);
                float hkA = bf2f(hkL[mA * 34 + h]);
                float hkB = bf2f(hkL[mB * 34 + h]);
#pragma unroll
                for (int r = 0; r < 2; ++r) {
                    float hqv = r ? hq1 : hq0;
#pragma unroll
                    for (int c = 0; c < 2; ++c) {
                        float hkv = c ? hkB : hkA;
                        float4 e = e4[r][c];
                        float he = fmaf(e.x, we.x, fmaf(e.y, we.y, fmaf(e.z, we.z, e.w * we.w)));
                        pacc[r][c] = fmaf(fmaxf(hqv + hkv + he, 0.f), w2v, pacc[r][c]);
                    }
                }
            }
            float cont[2][2] = {{a00, a01}, {a10, a11}};
#pragma unroll
            for (int r = 0; r < 2; ++r)
#pragma unroll
                for (int c = 0; c < 2; ++c) {
                    int n = n0 + r, m = c ? mB : mA;
                    float lg = cont[r][c] * 0.08838834764831845f
                             + pw * (pacc[r][c] + b2v) + prv[r][c];
                    if (maskrow[n] != 0.f || maskrow[m] != 0.f) lg = -1e9f;
                    Lg[n * 36 + m] = lg;
                }
        }
        __syncthreads();

        // ---- P4: wave-parallel softmax (8 lanes per row) ----
        {
            const int n = tid >> 3, q = tid & 7;
            float4 v = *(const float4*)(Lg + n * 36 + q * 4);
            float mx = fmaxf(fmaxf(v.x, v.y), fmaxf(v.z, v.w));
#pragma unroll
            for (int off = 1; off < 8; off <<= 1)
                mx = fmaxf(mx, __shfl_xor(mx, off, 64));
            float ex = __expf(v.x - mx), ey = __expf(v.y - mx),
                  ez = __expf(v.z - mx), ew = __expf(v.w - mx);
            float s = (ex + ey) + (ez + ew);
#pragma unroll
            for (int off = 1; off < 8; off <<= 1)
                s += __shfl_xor(s, off, 64);
            float inv = 1.f / s;
            float4 o; o.x = ex * inv; o.y = ey * inv; o.z = ez * inv; o.w = ew * inv;
            *(float4*)(Lg + n * 36 + q * 4) = o;
        }
        __syncthreads();

        const int rg = wv & 1, ch = wv >> 1;

        // ---- P6: thf prefetch (issued first, flies under spatial) + alpha@V
        bf16x8 thf[16];
#pragma unroll
        for (int nt = 0; nt < 4; ++nt)
#pragma unroll
            for (int ks = 0; ks < 4; ++ks)
                thf[nt * 4 + ks] = WfG[6144 + (((ch * 4 + nt) * 4 + ks) * 64) + lane];
        {
            const int vks = d0p >> 5, vq = (d0p >> 3) & 3, vj = d0p & 7;
            float sa[4][4] = {};
            for (int m = 0; m < 32; m += 4) {
                float alv[4][4];
#pragma unroll
                for (int r = 0; r < 4; ++r) {
                    float4 t = *(const float4*)(Lg + (ngp * 4 + r) * 36 + m);
                    alv[r][0] = t.x; alv[r][1] = t.y; alv[r][2] = t.z; alv[r][3] = t.w;
                }
#pragma unroll
                for (int mm = 0; mm < 4; ++mm) {
                    uint2 vv = *(const uint2*)(Vs + (m + mm) * 136 + d0p);
                    float v0 = bf2f((unsigned short)(vv.x & 0xffffu));
                    float v1 = bf2f((unsigned short)(vv.x >> 16));
                    float v2 = bf2f((unsigned short)(vv.y & 0xffffu));
                    float v3 = bf2f((unsigned short)(vv.y >> 16));
#pragma unroll
                    for (int r = 0; r < 4; ++r) {
                        float a = alv[r][mm];
                        sa[r][0] = fmaf(a, v0, sa[r][0]); sa[r][1] = fmaf(a, v1, sa[r][1]);
                        sa[r][2] = fmaf(a, v2, sa[r][2]); sa[r][3] = fmaf(a, v3, sa[r][3]);
                    }
                }
            }
            // Sfrag aliases Ks (dead after P3)
#pragma unroll
            for (int r = 0; r < 4; ++r) {
                int nloc = ngp * 4 + r;
                int tg = nloc >> 4, nl = nloc & 15;
                unsigned short* sp = Sfrag + ((tg * 4 + vks) * 64 + vq * 16 + nl) * 8 + vj;
                sp[0] = f2bf(sa[r][0]); sp[1] = f2bf(sa[r][1]);
                sp[2] = f2bf(sa[r][2]); sp[3] = f2bf(sa[r][3]);
            }
        }
        __syncthreads();

        // ---- P7: Theta MFMA -> ThOut (alias Qs, stride 132) ----
        {
            f32x4 aT[4] = {zero, zero, zero, zero};
            bf16x8 av0 = *(const bf16x8*)(Sfrag + ((rg * 4 + 0) * 64 + lane) * 8);
            bf16x8 av1 = *(const bf16x8*)(Sfrag + ((rg * 4 + 1) * 64 + lane) * 8);
            bf16x8 av2 = *(const bf16x8*)(Sfrag + ((rg * 4 + 2) * 64 + lane) * 8);
            bf16x8 av3 = *(const bf16x8*)(Sfrag + ((rg * 4 + 3) * 64 + lane) * 8);
#pragma unroll
            for (int nt = 0; nt < 4; ++nt) {
                aT[nt] = __builtin_amdgcn_mfma_f32_16x16x32_bf16(av0, thf[nt * 4 + 0], aT[nt], 0, 0, 0);
                aT[nt] = __builtin_amdgcn_mfma_f32_16x16x32_bf16(av1, thf[nt * 4 + 1], aT[nt], 0, 0, 0);
                aT[nt] = __builtin_amdgcn_mfma_f32_16x16x32_bf16(av2, thf[nt * 4 + 2], aT[nt], 0, 0, 0);
                aT[nt] = __builtin_amdgcn_mfma_f32_16x16x32_bf16(av3, thf[nt * 4 + 3], aT[nt], 0, 0, 0);
            }
#pragma unroll
            for (int nt = 0; nt < 4; ++nt) {
                int colc = ch * 64 + nt * 16 + col0;
#pragma unroll
                for (int reg = 0; reg < 4; ++reg)
                    ThOut[(rg * 16 + quad * 4 + reg) * 132 + colc] = aT[nt][reg];
            }
        }
        __syncthreads();

        // ---- P8: y = x + ThOut; LayerNorm; mask; store (4 rows/thread) ----
        {
#pragma unroll
            for (int r = 0; r < 4; ++r) {
                int nloc = ngp * 4 + r;
                const float* xr = x + ((size_t)((b_ * 32 + nloc) * 64 + t_)) * 128 + d0p;
                float4 z  = *(const float4*)(xr);
                float4 th = *(const float4*)(ThOut + nloc * 132 + d0p);
                float y0 = th.x + z.x, y1 = th.y + z.y, y2 = th.z + z.z, y3 = th.w + z.w;
                float s  = (y0 + y1) + (y2 + y3);
                float s2 = (y0*y0 + y1*y1) + (y2*y2 + y3*y3);
#pragma unroll
                for (int off = 1; off < 32; off <<= 1) {
                    s  += __shfl_xor(s,  off, 64);
                    s2 += __shfl_xor(s2, off, 64);
                }
                float mu   = s * 0.0078125f;
                float var  = s2 * 0.0078125f - mu * mu;
                float rstd = rsqrtf(var + 1e-5f);
                float msk  = (maskrow[nloc] != 0.f) ? 0.f : 1.f;
                float4 o;
                o.x = ((y0 - mu) * rstd * g4.x + be4.x) * msk;
                o.y = ((y1 - mu) * rstd * g4.y + be4.y) * msk;
                o.z = ((y2 - mu) * rstd * g4.z + be4.z) * msk;
                o.w = ((y3 - mu) * rstd * g4.w + be4.w) * msk;
                *(float4*)(out + ((size_t)((b_ * 32 + nloc) * 64 + t_)) * 128 + d0p) = o;
            }
        }
        __syncthreads();   // ThOut (Qs) must be dead before next bt's Zfrag
    }
}

// ===========================================================================
extern "C" void kernel_launch(void* const* d_in, const int* in_sizes, int n_in,
                              void* d_out, int out_size, void* d_ws, size_t ws_size,
                              hipStream_t stream) {
    const float* x        = (const float*)d_in[0];
    const float* edge     = (const float*)d_in[1];
    const float* A_prior  = (const float*)d_in[2];
    const unsigned char* pad_mask = (const unsigned char*)d_in[3];
    const float* Wq       = (const float*)d_in[4];
    const float* Wk       = (const float*)d_in[5];
    const float* Wv       = (const float*)d_in[6];
    const float* Theta    = (const float*)d_in[7];
    const float* Wfuse    = (const float*)d_in[8];
    const float* W1       = (const float*)d_in[9];
    const float* b1       = (const float*)d_in[10];
    const float* W2       = (const float*)d_in[11];
    const float* b2       = (const float*)d_in[12];
    const float* gma      = (const float*)d_in[13];
    const float* bta      = (const float*)d_in[14];
    const float* physw    = (const float*)d_in[15];
    const float* priorw   = (const float*)d_in[16];
    float* out = (float*)d_out;

    unsigned short* Wfrag = (unsigned short*)d_ws;   // 147456 B (9216 chunks)

    k0_prep<<<dim3(64), dim3(256), 0, stream>>>(Wq, Wk, Wv, Theta, W1, Wfrag);
    gnn_all<<<dim3(256), dim3(256), 0, stream>>>(
        x, edge, A_prior, pad_mask, Wfrag, Wfuse,
        W1, b1, W2, b2, gma, bta, physw, priorw, out);
}